// Round 1
// baseline (370.360 us; speedup 1.0000x reference)
//
#include <hip/hip_runtime.h>
#include <cmath>

#define HH 32
#define WW 32
#define HWN 1024
#define NCH 384
#define NHH 12
#define DHH 32
#define NGG 6

static constexpr float SCALE_QK = 0.17677669529663689f; // 32^-0.5

// ---------------------------------------------------------------------------
// K1/K4: fp32 GEMM  C[2048,N] = A[2048,K] @ W[K,N] + bias, 3-way z-select
// 64x64 tile, BK=16, 256 threads, 4x4 micro tile.
// ---------------------------------------------------------------------------
__global__ __launch_bounds__(256) void gemm3_kernel(
    const float* __restrict__ A,
    const float* __restrict__ W0, const float* __restrict__ W1, const float* __restrict__ W2,
    const float* __restrict__ b0, const float* __restrict__ b1, const float* __restrict__ b2,
    float* __restrict__ C0, float* __restrict__ C1, float* __restrict__ C2,
    int N, int K)
{
    const float* Wm = (blockIdx.z == 0) ? W0 : (blockIdx.z == 1) ? W1 : W2;
    const float* bm = (blockIdx.z == 0) ? b0 : (blockIdx.z == 1) ? b1 : b2;
    float*       Cm = (blockIdx.z == 0) ? C0 : (blockIdx.z == 1) ? C1 : C2;

    const int m0 = blockIdx.x * 64;
    const int n0 = blockIdx.y * 64;
    const int tid = threadIdx.x;
    const int tm = tid >> 4;   // 0..15
    const int tn = tid & 15;   // 0..15

    __shared__ float As[16][68];   // [k][m], +4 pad keeps 16B alignment, ~2-way banks
    __shared__ float Bs[16][68];   // [k][n]

    float acc[4][4] = {};

    for (int k0 = 0; k0 < K; k0 += 16) {
#pragma unroll
        for (int r = 0; r < 4; ++r) {
            int e = tid + r * 256;
            int row = e >> 4, kk = e & 15;
            As[kk][row] = A[(m0 + row) * K + k0 + kk];
            int kk2 = e >> 6, col = e & 63;
            Bs[kk2][col] = Wm[(k0 + kk2) * N + n0 + col];
        }
        __syncthreads();
#pragma unroll
        for (int kk = 0; kk < 16; ++kk) {
            float4 a4 = *(const float4*)&As[kk][tm * 4];
            float4 b4 = *(const float4*)&Bs[kk][tn * 4];
            float av[4] = {a4.x, a4.y, a4.z, a4.w};
            float bv[4] = {b4.x, b4.y, b4.z, b4.w};
#pragma unroll
            for (int i2 = 0; i2 < 4; ++i2)
#pragma unroll
                for (int j2 = 0; j2 < 4; ++j2)
                    acc[i2][j2] += av[i2] * bv[j2];
        }
        __syncthreads();
    }

#pragma unroll
    for (int i2 = 0; i2 < 4; ++i2) {
        float4 o4;
        o4.x = acc[i2][0] + bm[n0 + tn * 4 + 0];
        o4.y = acc[i2][1] + bm[n0 + tn * 4 + 1];
        o4.z = acc[i2][2] + bm[n0 + tn * 4 + 2];
        o4.w = acc[i2][3] + bm[n0 + tn * 4 + 3];
        *(float4*)&Cm[(m0 + tm * 4 + i2) * N + n0 + tn * 4] = o4;
    }
}

// ---------------------------------------------------------------------------
// K2: grouped 3x3 conv (SAME) on q  -> +b_off -> LayerNorm -> GELU(tanh)
//     -> per-group projection to 2 -> tanh*16 + ref -> pos (ws + d_out) + ref
// One block = 8 consecutive pixels of one row. 384 threads = 1 thread per
// output channel; wave w == channel group w (64 ch) so the offset projection
// is a pure wave reduction.
// ---------------------------------------------------------------------------
__global__ __launch_bounds__(384) void conv_offset_kernel(
    const float* __restrict__ q, const float* __restrict__ w_off,
    const float* __restrict__ b_off, const float* __restrict__ ln_g,
    const float* __restrict__ ln_b, const float* __restrict__ w_offp,
    float* __restrict__ pos_ws, float* __restrict__ pos_out,
    float* __restrict__ ref_out)
{
    const int b  = blockIdx.z;
    const int i  = blockIdx.y;
    const int j0 = blockIdx.x * 8;
    const int tid = threadIdx.x;      // output channel d
    const int g   = tid >> 6;         // group = wave id
    const int lane = tid & 63;        // channel within group

    __shared__ float qs[3][10][NCH];  // rows i-1..i+1, cols j0-1..j0+8
    __shared__ float red[6][8][2];

    for (int idx = tid; idx < 3 * 10 * NCH; idx += 384) {
        int r = idx / (10 * NCH);
        int rem = idx - r * (10 * NCH);
        int col = rem / NCH;
        int c = rem - col * NCH;
        int ii = i + r - 1;
        int jj = j0 + col - 1;
        float vv = 0.f;
        if (ii >= 0 && ii < HH && jj >= 0 && jj < WW)
            vv = q[((b * HH + ii) * WW + jj) * NCH + c];
        qs[r][col][c] = vv;
    }
    __syncthreads();

    const float bo0 = b_off[tid];
    float acc[8];
#pragma unroll
    for (int p = 0; p < 8; ++p) acc[p] = bo0;

    for (int r = 0; r < 3; ++r) {            // r == kh (input row i+r-1)
        for (int c4 = 0; c4 < 16; ++c4) {    // input-channel quad within group
            float wgt[3][4];
#pragma unroll
            for (int kw = 0; kw < 3; ++kw)
#pragma unroll
                for (int u = 0; u < 4; ++u)
                    wgt[kw][u] = w_off[(((r * 3 + kw) * 64) + c4 * 4 + u) * NCH + tid];
#pragma unroll
            for (int col = 0; col < 10; ++col) {
                float4 qv = *(const float4*)&qs[r][col][(g << 6) + c4 * 4];
#pragma unroll
                for (int kw = 0; kw < 3; ++kw) {
                    int p = col - kw;
                    if (p >= 0 && p < 8)
                        acc[p] += wgt[kw][0] * qv.x + wgt[kw][1] * qv.y
                                + wgt[kw][2] * qv.z + wgt[kw][3] * qv.w;
                }
            }
        }
    }

    // per-pixel LayerNorm stats over 384 channels
#pragma unroll
    for (int p = 0; p < 8; ++p) {
        float v = acc[p];
        float s1 = v, s2 = v * v;
#pragma unroll
        for (int off = 32; off > 0; off >>= 1) {
            s1 += __shfl_xor(s1, off);
            s2 += __shfl_xor(s2, off);
        }
        if (lane == 0) { red[g][p][0] = s1; red[g][p][1] = s2; }
    }
    __syncthreads();

    const float gain = ln_g[tid];
    const float beta = ln_b[tid];
    const float wp0 = w_offp[lane * 2 + 0];
    const float wp1 = w_offp[lane * 2 + 1];

#pragma unroll
    for (int p = 0; p < 8; ++p) {
        float s1 = 0.f, s2 = 0.f;
#pragma unroll
        for (int w2 = 0; w2 < 6; ++w2) { s1 += red[w2][p][0]; s2 += red[w2][p][1]; }
        float mu  = s1 * (1.f / 384.f);
        float var = s2 * (1.f / 384.f) - mu * mu;
        float rs2 = rsqrtf(var + 1e-3f);
        float on = (acc[p] - mu) * rs2 * gain + beta;
        float t = 0.7978845608028654f * (on + 0.044715f * on * on * on);
        float ge = on * 0.5f * (1.f + tanhf(t));

        float t0 = ge * wp0, t1 = ge * wp1;
#pragma unroll
        for (int off = 32; off > 0; off >>= 1) {
            t0 += __shfl_xor(t0, off);
            t1 += __shfl_xor(t1, off);
        }
        if (lane == 0) {
            int jj = j0 + p;
            float o0 = tanhf(t0) * 16.f + (float)jj;   // + ref.x (= col j)
            float o1 = tanhf(t1) * 16.f + (float)i;    // + ref.y (= row i)
            int base = (((b * NGG + g) * HWN) + i * WW + jj) * 2;
            pos_ws[base]      = o0; pos_ws[base + 1]  = o1;
            pos_out[base]     = o0; pos_out[base + 1] = o1;
            ref_out[base]     = (float)jj; ref_out[base + 1] = (float)i;
        }
    }
}

// ---------------------------------------------------------------------------
// K3: fused attention. Block = 64 queries x 4 key-chunk waves (256 threads).
// Thread owns one query: q in regs, K/V rows read with wave-uniform addresses
// (scalarizable), RPE bias bilinear-sampled from an LDS-staged [63][63] slice
// (stride 63 == -1 mod 32 banks -> conflict-free), defer-max online softmax,
// in-block LDS combine of the 4 chunk partials.
// ---------------------------------------------------------------------------
__global__ __launch_bounds__(256) void attn_kernel(
    const float* __restrict__ q_ws, const float* __restrict__ k_ws,
    const float* __restrict__ v_ws, const float* __restrict__ pos_ws,
    const float* __restrict__ rpe, float* __restrict__ o_ws)
{
    const int bh = blockIdx.y;
    const int b = bh / NHH;
    const int h = bh - b * NHH;
    const int g = h >> 1;
    const int tid = threadIdx.x;
    const int wv = tid >> 6;          // key chunk 0..3
    const int lane = tid & 63;
    const int qn = blockIdx.x * 64 + lane;

    __shared__ float rs[63 * 63];
    __shared__ float accs[4][DHH][64];
    __shared__ float mls[4][2][64];

    for (int idx = tid; idx < 63 * 63; idx += 256)
        rs[idx] = rpe[idx * NHH + h];

    float ql[DHH];
    {
        const float* qp = q_ws + ((b * HWN) + qn) * NCH + h * DHH;
#pragma unroll
        for (int d4 = 0; d4 < 8; ++d4) {
            float4 t = *(const float4*)(qp + d4 * 4);
            ql[d4 * 4 + 0] = t.x * SCALE_QK;
            ql[d4 * 4 + 1] = t.y * SCALE_QK;
            ql[d4 * 4 + 2] = t.z * SCALE_QK;
            ql[d4 * 4 + 3] = t.w * SCALE_QK;
        }
    }
    const float fi = (float)(qn >> 5);
    const float fj = (float)(qn & 31);

    float m = -1e30f, l = 0.f;
    float acc[DHH];
#pragma unroll
    for (int d = 0; d < DHH; ++d) acc[d] = 0.f;

    __syncthreads();

    const float* kb = k_ws + (b * HWN) * NCH + h * DHH;
    const float* vb = v_ws + (b * HWN) * NCH + h * DHH;
    const float* pb = pos_ws + (b * NGG + g) * (HWN * 2);

    const int send = wv * 256 + 256;
    for (int s = wv * 256; s < send; ++s) {
        const float* kr = kb + s * NCH;
        float sc = 0.f;
#pragma unroll
        for (int d = 0; d < DHH; ++d) sc += kr[d] * ql[d];

        const float p0 = pb[s * 2 + 0];
        const float p1 = pb[s * 2 + 1];
        float xw = fi - p1;
        float yw = fj - p0;
        float x0f = floorf(xw), y0f = floorf(yw);
        float wx = xw - x0f, wy = yw - y0f;
        int ix = (int)x0f, iy = (int)y0f;
        int cx0 = min(max(ix, 0), 62), cx1 = min(max(ix + 1, 0), 62);
        int cy0 = min(max(iy, 0), 62), cy1 = min(max(iy + 1, 0), 62);
        float fx0 = (ix >= 0 && ix < 63) ? 1.f : 0.f;
        float fx1 = (ix + 1 >= 0 && ix + 1 < 63) ? 1.f : 0.f;
        float fy0 = (iy >= 0 && iy < 63) ? 1.f : 0.f;
        float fy1 = (iy + 1 >= 0 && iy + 1 < 63) ? 1.f : 0.f;
        float v00 = rs[cy0 * 63 + cx0] * (fy0 * fx0);
        float v01 = rs[cy0 * 63 + cx1] * (fy0 * fx1);
        float v10 = rs[cy1 * 63 + cx0] * (fy1 * fx0);
        float v11 = rs[cy1 * 63 + cx1] * (fy1 * fx1);
        float bias = (v00 * (1.f - wx) + v01 * wx) * (1.f - wy)
                   + (v10 * (1.f - wx) + v11 * wx) * wy;
        sc += bias;

        if (sc > m + 8.f) {          // defer-max rescale (rare)
            float scl = __expf(m - sc);
            m = sc;
            l *= scl;
#pragma unroll
            for (int d = 0; d < DHH; ++d) acc[d] *= scl;
        }
        float pr = __expf(sc - m);
        l += pr;
        const float* vr = vb + s * NCH;
#pragma unroll
        for (int d = 0; d < DHH; ++d) acc[d] += pr * vr[d];
    }

    mls[wv][0][lane] = m;
    mls[wv][1][lane] = l;
#pragma unroll
    for (int d = 0; d < DHH; ++d) accs[wv][d][lane] = acc[d];
    __syncthreads();

    const int q2 = tid & 63;
    const int dq = (tid >> 6) * 8;
    const int qn2 = blockIdx.x * 64 + q2;
    float mm0 = mls[0][0][q2], mm1 = mls[1][0][q2];
    float mm2 = mls[2][0][q2], mm3 = mls[3][0][q2];
    float mstar = fmaxf(fmaxf(mm0, mm1), fmaxf(mm2, mm3));
    float w0 = __expf(mm0 - mstar), w1 = __expf(mm1 - mstar);
    float w2 = __expf(mm2 - mstar), w3 = __expf(mm3 - mstar);
    float lsum = w0 * mls[0][1][q2] + w1 * mls[1][1][q2]
               + w2 * mls[2][1][q2] + w3 * mls[3][1][q2];
    float inv = 1.f / lsum;
    float* op = o_ws + ((b * HWN) + qn2) * NCH + h * DHH + dq;
#pragma unroll
    for (int u = 0; u < 8; ++u) {
        float o = w0 * accs[0][dq + u][q2] + w1 * accs[1][dq + u][q2]
                + w2 * accs[2][dq + u][q2] + w3 * accs[3][dq + u][q2];
        op[u] = o * inv;
    }
}

// ---------------------------------------------------------------------------
extern "C" void kernel_launch(void* const* d_in, const int* in_sizes, int n_in,
                              void* d_out, int out_size, void* d_ws, size_t ws_size,
                              hipStream_t stream) {
    (void)in_sizes; (void)n_in; (void)out_size; (void)ws_size;
    const float* x      = (const float*)d_in[0];
    const float* w_off  = (const float*)d_in[1];
    const float* b_off  = (const float*)d_in[2];
    const float* ln_g   = (const float*)d_in[3];
    const float* ln_b   = (const float*)d_in[4];
    const float* w_offp = (const float*)d_in[5];
    const float* wq     = (const float*)d_in[6];
    const float* bq     = (const float*)d_in[7];
    const float* wk     = (const float*)d_in[8];
    const float* bk     = (const float*)d_in[9];
    const float* wv     = (const float*)d_in[10];
    const float* bv     = (const float*)d_in[11];
    const float* wo     = (const float*)d_in[12];
    const float* bo     = (const float*)d_in[13];
    const float* rpe    = (const float*)d_in[14];

    float* out     = (float*)d_out;
    float* y_out   = out;             // 786432
    float* pos_out = out + 786432;    // 24576
    float* ref_out = out + 811008;    // 24576

    float* ws     = (float*)d_ws;
    float* q_ws   = ws;               // 786432
    float* k_ws   = ws + 786432;      // 786432
    float* v_ws   = ws + 1572864;     // 786432
    float* o_ws   = ws + 2359296;     // 786432
    float* pos_ws = ws + 3145728;     // 24576

    // K1: q/k/v projections (one launch, z selects weight/output)
    gemm3_kernel<<<dim3(32, 6, 3), 256, 0, stream>>>(
        x, wq, wk, wv, bq, bk, bv, q_ws, k_ws, v_ws, NCH, NCH);

    // K2: grouped conv + LN + GELU + offset -> pos (+ pos/ref outputs)
    conv_offset_kernel<<<dim3(4, 32, 2), 384, 0, stream>>>(
        q_ws, w_off, b_off, ln_g, ln_b, w_offp, pos_ws, pos_out, ref_out);

    // K3: fused attention with bilinear RPE bias
    attn_kernel<<<dim3(16, 24), 256, 0, stream>>>(
        q_ws, k_ws, v_ws, pos_ws, rpe, o_ws);

    // K4: output projection -> y
    gemm3_kernel<<<dim3(32, 6, 1), 256, 0, stream>>>(
        o_ws, wo, wo, wo, bo, bo, bo, y_out, y_out, y_out, NCH, NCH);
}